// Round 1
// baseline (65.996 us; speedup 1.0000x reference)
//
#include <hip/hip_runtime.h>

typedef __bf16 v8bf __attribute__((ext_vector_type(8)));
typedef __bf16 v4bf __attribute__((ext_vector_type(4)));
typedef float f32x4 __attribute__((ext_vector_type(4)));

#define NB 8
#define MM 128
#define DD 64

// ---------------- Kernel 1: row sums, col sums, diag extraction ----------------
// grid 1024 (= n*128 + i), block 256
__global__ void k_rowcol(const float* __restrict__ x, float* __restrict__ rowS,
                         float* __restrict__ colS, float* __restrict__ diagS) {
    int b = blockIdx.x;
    int n = b >> 7, i = b & 127;
    int t = threadIdx.x;
    int d = t & 63, c = t >> 6;
    const float* xn = x + (size_t)n * MM * MM * DD;
    float ar = 0.f, ac = 0.f;
    for (int j = c; j < MM; j += 4) {
        ar += xn[(i * MM + j) * DD + d];   // row[i] = sum_j x[i,j,d]
        ac += xn[(j * MM + i) * DD + d];   // col[i] = sum_k x[k,i,d]
    }
    __shared__ float sr[256], sc[256];
    sr[t] = ar; sc[t] = ac;
    __syncthreads();
    if (t < 64) {
        float r = sr[t] + sr[t + 64] + sr[t + 128] + sr[t + 192];
        float cc = sc[t] + sc[t + 64] + sc[t + 128] + sc[t + 192];
        rowS[b * DD + t] = r;
        colS[b * DD + t] = cc;
        diagS[b * DD + t] = xn[(i * MM + i) * DD + t];
    }
}

// ---------------- Kernel 2: per-n trace and total sums ----------------
// grid 8, block 256
__global__ void k_nsum(const float* __restrict__ rowS, const float* __restrict__ diagS,
                       float* __restrict__ sd, float* __restrict__ sa) {
    int n = blockIdx.x;
    int t = threadIdx.x;
    int d = t & 63, c = t >> 6;
    float asd = 0.f, asa = 0.f;
    for (int i = c; i < MM; i += 4) {
        asd += diagS[(n * MM + i) * DD + d];
        asa += rowS[(n * MM + i) * DD + d];
    }
    __shared__ float s1[256], s2[256];
    s1[t] = asd; s2[t] = asa;
    __syncthreads();
    if (t < 64) {
        sd[n * DD + t] = s1[t] + s1[t + 64] + s1[t + 128] + s1[t + 192];
        sa[n * DD + t] = s2[t] + s2[t + 64] + s2[t + 128] + s2[t + 192];
    }
}

// ---------------- Kernel 3: repack coefs ----------------
// Crep[b][d][s] f32 planes; C1T/C2T = bf16 [s][d] (B^T layout for MFMA B-fragments)
// grid 240, block 256  (240*256 = 61440 = 64*64*15)
__global__ void k_repack(const float* __restrict__ coefs, float* __restrict__ Crep,
                         __bf16* __restrict__ C1T, __bf16* __restrict__ C2T) {
    int t = blockIdx.x * 256 + threadIdx.x;
    if (t >= DD * DD * 15) return;
    float v = coefs[t];
    int b = t % 15;
    int q = t / 15;          // = d*64 + s
    int s = q & 63, d = q >> 6;
    Crep[b * 4096 + d * 64 + s] = v;
    if (b == 0) C1T[s * 64 + d] = (__bf16)v;
    else if (b == 1) C2T[s * 64 + d] = (__bf16)v;
}

// ---------------- Kernel 4: projections F, G, Dd ----------------
// F[n,i,s] = sum_d (b4*diag + b11*col + b12*row + b13*sd + b14*sa) + bias[s]
// G[n,j,s] = sum_d (b3*diag + b9*col + b10*row)
// Dd[n,i,s]= sum_d (b2*diag + b6*row + b7*col + b5*sd + b8*sa) + diag_bias[s]
// grid 256, block 256 (4 rows of (n,i) per block, lane = s)
__global__ void k_proj(const float* __restrict__ rowS, const float* __restrict__ colS,
                       const float* __restrict__ diagS, const float* __restrict__ sd,
                       const float* __restrict__ sa, const float* __restrict__ Crep,
                       const float* __restrict__ bias, const float* __restrict__ diag_bias,
                       float* __restrict__ F, float* __restrict__ G, float* __restrict__ Dd) {
    int r = blockIdx.x * 4 + (threadIdx.x >> 6);   // (n,i) flat row, 0..1023
    int s = threadIdx.x & 63;
    int n = r >> 7;
    float aF = bias[s], aG = 0.f, aD = diag_bias[s];
    for (int d = 0; d < 64; ++d) {
        float dg = diagS[r * 64 + d];
        float cl = colS[r * 64 + d];
        float rw = rowS[r * 64 + d];
        float sdv = sd[n * 64 + d];
        float sav = sa[n * 64 + d];
        int o = d * 64 + s;
        aF += Crep[4 * 4096 + o] * dg + Crep[11 * 4096 + o] * cl + Crep[12 * 4096 + o] * rw
            + Crep[13 * 4096 + o] * sdv + Crep[14 * 4096 + o] * sav;
        aG += Crep[3 * 4096 + o] * dg + Crep[9 * 4096 + o] * cl + Crep[10 * 4096 + o] * rw;
        aD += Crep[2 * 4096 + o] * dg + Crep[6 * 4096 + o] * rw + Crep[7 * 4096 + o] * cl
            + Crep[5 * 4096 + o] * sdv + Crep[8 * 4096 + o] * sav;
    }
    F[r * 64 + s] = aF;
    G[r * 64 + s] = aG;
    Dd[r * 64 + s] = aD;
}

// ---------------- Kernel 5: main MFMA kernel ----------------
// Block: 64 pairs (fixed n, fixed i, j in [j0, j0+64)), 256 threads = 4 waves.
// out[p, s] = X[p,:]*C1 + XT[p,:]*C2 (bf16 MFMA) + F + G + (i==j)*Dd, leakyrelu, *mask
__global__ __launch_bounds__(256) void k_main(
        const float* __restrict__ x, const float* __restrict__ mask,
        const float* __restrict__ F, const float* __restrict__ G,
        const float* __restrict__ Dd, const __bf16* __restrict__ C1T,
        const __bf16* __restrict__ C2T, float* __restrict__ out) {
    __shared__ __bf16 Xs[64][72];    // pad 64->72 (144B row stride) to break bank conflicts
    __shared__ __bf16 XTs[64][72];
    __shared__ __bf16 C1s[64][72];   // [s][d]
    __shared__ __bf16 C2s[64][72];

    int bid = blockIdx.x;
    int n = bid >> 8;
    int tt = bid & 255;
    int i = tt >> 1;
    int j0 = (tt & 1) << 6;
    int tid = threadIdx.x;

    const float* xn = x + (size_t)n * MM * MM * DD;
    const float* xid = xn + (i * MM + j0) * DD;   // identity tile: contiguous 4096 floats

    // stage identity tile (rows r -> pair (i, j0+r))
    #pragma unroll
    for (int c = 0; c < 4; ++c) {
        int v = c * 256 + tid;            // float4 index 0..1023
        float4 f4 = ((const float4*)xid)[v];
        int r = v >> 4, d0 = (v & 15) << 2;
        v4bf b = {(__bf16)f4.x, (__bf16)f4.y, (__bf16)f4.z, (__bf16)f4.w};
        *(v4bf*)&Xs[r][d0] = b;
    }
    // stage transpose tile: row r -> x[n, j0+r, i, :]
    #pragma unroll
    for (int c = 0; c < 4; ++c) {
        int v = c * 256 + tid;
        int r = v >> 4, d0 = (v & 15) << 2;
        float4 f4 = *(const float4*)(xn + ((size_t)(j0 + r) * MM + i) * DD + d0);
        v4bf b = {(__bf16)f4.x, (__bf16)f4.y, (__bf16)f4.z, (__bf16)f4.w};
        *(v4bf*)&XTs[r][d0] = b;
    }
    // stage coef matrices (already bf16, [s][d] layout)
    #pragma unroll
    for (int c = 0; c < 4; ++c) {
        int v = c * 256 + tid;            // v4bf index 0..1023
        int s = v >> 4, d0 = (v & 15) << 2;
        *(v4bf*)&C1s[s][d0] = ((const v4bf*)C1T)[v];
        *(v4bf*)&C2s[s][d0] = ((const v4bf*)C2T)[v];
    }
    __syncthreads();

    int w = tid >> 6, l = tid & 63;
    int lr = l & 15, hi = l >> 4;
    int arow = w * 16 + lr;

    f32x4 acc[4];
    #pragma unroll
    for (int st = 0; st < 4; ++st) acc[st] = (f32x4){0.f, 0.f, 0.f, 0.f};

    #pragma unroll
    for (int kk = 0; kk < 2; ++kk) {
        int ko = kk * 32 + hi * 8;
        v8bf a1 = *(const v8bf*)&Xs[arow][ko];
        v8bf a2 = *(const v8bf*)&XTs[arow][ko];
        #pragma unroll
        for (int st = 0; st < 4; ++st) {
            v8bf b1 = *(const v8bf*)&C1s[st * 16 + lr][ko];
            v8bf b2 = *(const v8bf*)&C2s[st * 16 + lr][ko];
            acc[st] = __builtin_amdgcn_mfma_f32_16x16x32_bf16(a1, b1, acc[st], 0, 0, 0);
            acc[st] = __builtin_amdgcn_mfma_f32_16x16x32_bf16(a2, b2, acc[st], 0, 0, 0);
        }
    }

    // epilogue: C/D layout col = lane&15, row = (lane>>4)*4 + q
    int base_i = n * MM + i;
    const float* Fp = F + base_i * 64;
    const float* Dp = Dd + base_i * 64;
    const float* Gn = G + n * MM * 64;
    const float* mrow = mask + (size_t)base_i * MM + j0;
    float* outp = out + ((size_t)base_i * MM + j0) * 64;

    #pragma unroll
    for (int st = 0; st < 4; ++st) {
        int s = st * 16 + lr;
        float Fv = Fp[s];
        float Dv = Dp[s];
        #pragma unroll
        for (int q = 0; q < 4; ++q) {
            int r = w * 16 + hi * 4 + q;   // local row
            int j = j0 + r;
            float v = acc[st][q] + Fv + Gn[j * 64 + s];
            if (i == j) v += Dv;
            v = v > 0.f ? v : 0.01f * v;
            v *= mrow[r];
            outp[(size_t)r * 64 + s] = v;
        }
    }
}

extern "C" void kernel_launch(void* const* d_in, const int* in_sizes, int n_in,
                              void* d_out, int out_size, void* d_ws, size_t ws_size,
                              hipStream_t stream) {
    const float* x = (const float*)d_in[0];
    // d_in[1] = nobj (unused: config 's' -> no rescale)
    const float* mask = (const float*)d_in[2];
    const float* coefs = (const float*)d_in[3];
    const float* bias = (const float*)d_in[4];
    const float* diag_bias = (const float*)d_in[5];
    float* out = (float*)d_out;

    float* w0 = (float*)d_ws;
    float* rowS = w0;                 // 65536
    float* colS = w0 + 65536;         // 65536
    float* diagS = w0 + 131072;       // 65536
    float* sd = w0 + 196608;          // 512
    float* sa = w0 + 197120;          // 512
    float* F = w0 + 197632;           // 65536
    float* G = w0 + 263168;           // 65536
    float* Dd = w0 + 328704;          // 65536
    float* Crep = w0 + 394240;        // 61440
    __bf16* C1T = (__bf16*)(w0 + 455680);   // 4096 bf16
    __bf16* C2T = (__bf16*)(w0 + 457728);   // 4096 bf16

    k_rowcol<<<dim3(1024), dim3(256), 0, stream>>>(x, rowS, colS, diagS);
    k_nsum<<<dim3(8), dim3(256), 0, stream>>>(rowS, diagS, sd, sa);
    k_repack<<<dim3(240), dim3(256), 0, stream>>>(coefs, Crep, C1T, C2T);
    k_proj<<<dim3(256), dim3(256), 0, stream>>>(rowS, colS, diagS, sd, sa, Crep,
                                                bias, diag_bias, F, G, Dd);
    k_main<<<dim3(2048), dim3(256), 0, stream>>>(x, mask, F, G, Dd, C1T, C2T, out);
}